// Round 1
// baseline (2010.987 us; speedup 1.0000x reference)
//
#include <hip/hip_runtime.h>
#include <math.h>

// Problem constants
constexpr int Bn = 4, Tn = 1024, Cn = 1024, Hn = 16, Vh = 64;
constexpr int BT = Bn * Tn;                 // 4096
constexpr long long BTC = (long long)BT * Cn;  // 4M elements

// ---------------------------------------------------------------------------
// Kernel 1: mix input for the token-mix LoRA: out = x + (x_prev - x)*x_maa[c]
// ---------------------------------------------------------------------------
__global__ __launch_bounds__(256) void prep_mixin(const float* __restrict__ x,
                                                  const float* __restrict__ x_maa,
                                                  float* __restrict__ out) {
    long long idx = (long long)blockIdx.x * 256 + threadIdx.x;
    if (idx >= BTC) return;
    int c  = (int)(idx & (Cn - 1));
    long long bt = idx >> 10;
    int t  = (int)(bt & (Tn - 1));
    float xv = x[idx];
    float xp = (t > 0) ? x[idx - Cn] : 0.f;
    out[idx] = xv + (xp - xv) * x_maa[c];
}

// ---------------------------------------------------------------------------
// Generic f32 tiled GEMM: C[M,N] = A[M,K] @ B[K,N], with epilogues.
// BM=BN=64, BK=16, 256 threads, 4x4 micro-tile.
// EPI: 0 none, 1 tanh, 2 silu, 3 decay (exp(-exp(extra[col]+acc)))
// Requires: M % 64 == 0, K % 16 == 0. N guarded.
// ---------------------------------------------------------------------------
template <int EPI>
__global__ __launch_bounds__(256) void gemm_f32(const float* __restrict__ A,
                                                const float* __restrict__ Bm,
                                                float* __restrict__ C,
                                                int M, int N, int K,
                                                const float* __restrict__ extra) {
    __shared__ float As[16][64];
    __shared__ float Bs[16][64];
    int tid = threadIdx.x;
    int m0 = blockIdx.y * 64, n0 = blockIdx.x * 64;
    int tx = tid & 15, ty = tid >> 4;
    int ar = tid >> 2, ac = (tid & 3) * 4;   // A tile load coords
    int br = tid >> 4, bc = (tid & 15) * 4;  // B tile load coords
    float acc[4][4] = {};

    for (int k0 = 0; k0 < K; k0 += 16) {
        // Load A 64x16 tile (row-major, vectorized)
        const float* ap = A + (size_t)(m0 + ar) * K + k0 + ac;
        float4 av = *reinterpret_cast<const float4*>(ap);
        As[ac + 0][ar] = av.x; As[ac + 1][ar] = av.y;
        As[ac + 2][ar] = av.z; As[ac + 3][ar] = av.w;
        // Load B 16x64 tile with N guard
        float4 bv;
        if (n0 + bc + 3 < N) {
            bv = *reinterpret_cast<const float4*>(Bm + (size_t)(k0 + br) * N + n0 + bc);
        } else {
            float tmp[4];
            #pragma unroll
            for (int i = 0; i < 4; i++) {
                int col = n0 + bc + i;
                tmp[i] = (col < N) ? Bm[(size_t)(k0 + br) * N + col] : 0.f;
            }
            bv = make_float4(tmp[0], tmp[1], tmp[2], tmp[3]);
        }
        *reinterpret_cast<float4*>(&Bs[br][bc]) = bv;
        __syncthreads();
        #pragma unroll
        for (int kk = 0; kk < 16; kk++) {
            float4 a4 = *reinterpret_cast<const float4*>(&As[kk][ty * 4]);
            float4 b4 = *reinterpret_cast<const float4*>(&Bs[kk][tx * 4]);
            float aa[4] = {a4.x, a4.y, a4.z, a4.w};
            float bb[4] = {b4.x, b4.y, b4.z, b4.w};
            #pragma unroll
            for (int i = 0; i < 4; i++)
                #pragma unroll
                for (int j = 0; j < 4; j++)
                    acc[i][j] = fmaf(aa[i], bb[j], acc[i][j]);
        }
        __syncthreads();
    }

    #pragma unroll
    for (int i = 0; i < 4; i++) {
        int row = m0 + ty * 4 + i;
        #pragma unroll
        for (int j = 0; j < 4; j++) {
            int col = n0 + tx * 4 + j;
            if (col < N) {
                float v = acc[i][j];
                if (EPI == 1) v = tanhf(v);
                else if (EPI == 2) v = v / (1.f + expf(-v));        // silu
                else if (EPI == 3) v = expf(-expf(extra[col] + v)); // decay
                C[(size_t)row * N + col] = v;
            }
        }
    }
}

// ---------------------------------------------------------------------------
// Kernel: 5 mix deltas (mix160 @ tm_w2[f]) fused with wx/kx/vx/rx/gx build.
// One block per bt row.
// ---------------------------------------------------------------------------
__global__ __launch_bounds__(256) void deltas_mix(const float* __restrict__ x,
                                                  const float* __restrict__ mix160,
                                                  const float* __restrict__ w2,
                                                  const float* __restrict__ wmaa,
                                                  const float* __restrict__ kmaa,
                                                  const float* __restrict__ vmaa,
                                                  const float* __restrict__ rmaa,
                                                  const float* __restrict__ gmaa,
                                                  float* __restrict__ wx,
                                                  float* __restrict__ kx,
                                                  float* __restrict__ vx,
                                                  float* __restrict__ rx,
                                                  float* __restrict__ gx) {
    int bt = blockIdx.x;
    int t = bt & (Tn - 1);
    __shared__ float m[160];
    if (threadIdx.x < 160) m[threadIdx.x] = mix160[(size_t)bt * 160 + threadIdx.x];
    __syncthreads();
    for (int c = threadIdx.x; c < Cn; c += 256) {
        size_t idx = (size_t)bt * Cn + c;
        float xv = x[idx];
        float xp = (t > 0) ? x[idx - Cn] : 0.f;
        float sx = xp - xv;
        float d[5];
        #pragma unroll
        for (int f = 0; f < 5; f++) {
            float acc = 0.f;
            #pragma unroll
            for (int dd = 0; dd < 32; dd++)
                acc = fmaf(m[f * 32 + dd], w2[(size_t)(f * 32 + dd) * Cn + c], acc);
            d[f] = acc;
        }
        wx[idx] = xv + sx * (wmaa[c] + d[0]);
        kx[idx] = xv + sx * (kmaa[c] + d[1]);
        vx[idx] = xv + sx * (vmaa[c] + d[2]);
        rx[idx] = xv + sx * (rmaa[c] + d[3]);
        gx[idx] = xv + sx * (gmaa[c] + d[4]);
    }
}

// ---------------------------------------------------------------------------
// WKV6 recurrence. One block per (b,h). 4 waves: wave kg owns k in
// [kg*16, kg*16+16), lane owns v-column. State s[16] in registers.
// y_t[v] = sum_k r_k*(s_kv + u_k*k_k*v_v);  s_kv = w_k*s_kv + k_k*v_v
// ---------------------------------------------------------------------------
__global__ __launch_bounds__(256) void rwkv_rec(const float* __restrict__ r,
                                                const float* __restrict__ k,
                                                const float* __restrict__ v,
                                                const float* __restrict__ w,
                                                const float* __restrict__ tf,
                                                float* __restrict__ y) {
    int bh = blockIdx.x;              // b*H + h
    int b = bh >> 4, h = bh & 15;
    int tid = threadIdx.x;
    int lane = tid & 63;
    int kg = tid >> 6;                // 0..3
    int k0 = kg * 16;
    __shared__ float ls_r[64], ls_k[64], ls_w[64];
    __shared__ float part[4][64];
    float u[16], s[16];
    #pragma unroll
    for (int j = 0; j < 16; j++) {
        u[j] = tf[h * 64 + k0 + j];
        s[j] = 0.f;
    }
    for (int t = 0; t < Tn; t++) {
        size_t base = ((size_t)(b * Tn + t) * Hn + h) * 64;
        if (tid < 64)        ls_r[tid]       = r[base + tid];
        else if (tid < 128)  ls_k[tid - 64]  = k[base + tid - 64];
        else if (tid < 192)  ls_w[tid - 128] = w[base + tid - 128];
        __syncthreads();
        float vv = v[base + lane];
        float yp = 0.f;
        #pragma unroll
        for (int j = 0; j < 16; j++) {
            float kk = ls_k[k0 + j];
            float kv = kk * vv;
            yp = fmaf(ls_r[k0 + j], s[j] + u[j] * kv, yp);
            s[j] = fmaf(ls_w[k0 + j], s[j], kv);
        }
        part[kg][lane] = yp;
        __syncthreads();
        if (tid < 64)
            y[base + tid] = part[0][tid] + part[1][tid] + part[2][tid] + part[3][tid];
        // barrier at top of next iteration protects part[][] reads
    }
}

// ---------------------------------------------------------------------------
// GroupNorm per (bt,h) over 64 channels (after /8), *ln_w + ln_b, then *g.
// 4 waves per block, one group per wave.
// ---------------------------------------------------------------------------
__global__ __launch_bounds__(256) void gn_mul(const float* __restrict__ y,
                                              const float* __restrict__ g,
                                              const float* __restrict__ lnw,
                                              const float* __restrict__ lnb,
                                              float* __restrict__ fin) {
    int tid = threadIdx.x;
    int lane = tid & 63;
    int wv = tid >> 6;
    int grp = blockIdx.x * 4 + wv;    // bt*16 + h
    int h = grp & 15;
    size_t idx = (size_t)grp * 64 + lane;
    float val = y[idx] * 0.125f;      // / head_size_divisor
    float sum = val, sq = val * val;
    #pragma unroll
    for (int off = 32; off > 0; off >>= 1) {
        sum += __shfl_xor(sum, off, 64);
        sq  += __shfl_xor(sq,  off, 64);
    }
    float mu = sum * (1.f / 64.f);
    float var = sq * (1.f / 64.f) - mu * mu;
    float rs = rsqrtf(var + 1e-5f);
    float o = (val - mu) * rs * lnw[h * 64 + lane] + lnb[h * 64 + lane];
    fin[idx] = o * g[idx];
}

// ---------------------------------------------------------------------------
extern "C" void kernel_launch(void* const* d_in, const int* in_sizes, int n_in,
                              void* d_out, int out_size, void* d_ws, size_t ws_size,
                              hipStream_t stream) {
    (void)in_sizes; (void)n_in; (void)out_size; (void)ws_size;
    const float* x      = (const float*)d_in[0];
    const float* x_maa  = (const float*)d_in[1];
    const float* w_maa  = (const float*)d_in[2];
    const float* k_maa  = (const float*)d_in[3];
    const float* v_maa  = (const float*)d_in[4];
    const float* r_maa  = (const float*)d_in[5];
    const float* g_maa  = (const float*)d_in[6];
    const float* tm_w1  = (const float*)d_in[7];   // [C, 160]
    const float* tm_w2  = (const float*)d_in[8];   // [5, 32, C]
    const float* td_w1  = (const float*)d_in[9];   // [C, 64]
    const float* td_w2  = (const float*)d_in[10];  // [64, C]
    const float* t_dec  = (const float*)d_in[11];  // [H, 64] flat 1024
    const float* t_first= (const float*)d_in[12];  // [H, 64] flat 1024
    const float* Wr     = (const float*)d_in[13];
    const float* Wk     = (const float*)d_in[14];
    const float* Wv     = (const float*)d_in[15];
    const float* Wg     = (const float*)d_in[16];
    const float* Wo     = (const float*)d_in[17];
    const float* ln_w   = (const float*)d_in[18];
    const float* ln_b   = (const float*)d_in[19];
    float* out = (float*)d_out;

    // Workspace layout (floats). Total ~36.9M floats ~= 148 MB.
    float* ws = (float*)d_ws;
    size_t off = 0;
    auto alloc = [&](size_t n) { float* p = ws + off; off += n; return p; };
    float* mixin  = alloc(BTC);            // also reused as r-projection output
    float* mix160 = alloc((size_t)BT * 160);
    float* wx = alloc(BTC);
    float* kx = alloc(BTC);
    float* vx = alloc(BTC);
    float* rx = alloc(BTC);
    float* gx = alloc(BTC);
    float* kb = alloc(BTC);
    float* vb = alloc(BTC);
    float* gb = alloc(BTC);
    float* wl1 = alloc((size_t)BT * 64);
    // Buffer reuse (stream-ordered, producers complete before reuse):
    float* rb   = mixin;  // r projection (mixin dead after GEMM1)
    float* wdec = vx;     // decay w (vx dead after v projection)
    float* ybuf = wx;     // recurrence out (wx dead after wl1 GEMM)
    float* fin  = kx;     // groupnorm*g out (kx dead after k projection)

    dim3 blk(256);
    // 1. mix input
    prep_mixin<<<dim3((unsigned)((BTC + 255) / 256)), blk, 0, stream>>>(x, x_maa, mixin);
    // 2. LoRA GEMM1 + tanh: [4096,1024]@[1024,160]
    gemm_f32<1><<<dim3(3, 64), blk, 0, stream>>>(mixin, tm_w1, mix160, BT, 160, Cn, nullptr);
    // 3. mix deltas + build wx/kx/vx/rx/gx
    deltas_mix<<<dim3(BT), blk, 0, stream>>>(x, mix160, tm_w2,
                                             w_maa, k_maa, v_maa, r_maa, g_maa,
                                             wx, kx, vx, rx, gx);
    // 4. projections
    gemm_f32<0><<<dim3(16, 64), blk, 0, stream>>>(rx, Wr, rb, BT, Cn, Cn, nullptr);
    gemm_f32<0><<<dim3(16, 64), blk, 0, stream>>>(kx, Wk, kb, BT, Cn, Cn, nullptr);
    gemm_f32<0><<<dim3(16, 64), blk, 0, stream>>>(vx, Wv, vb, BT, Cn, Cn, nullptr);
    gemm_f32<2><<<dim3(16, 64), blk, 0, stream>>>(gx, Wg, gb, BT, Cn, Cn, nullptr);
    // 5. decay LoRA: tanh(wx@td_w1) then exp(-exp(td + @td_w2))
    gemm_f32<1><<<dim3(1, 64), blk, 0, stream>>>(wx, td_w1, wl1, BT, 64, Cn, nullptr);
    gemm_f32<3><<<dim3(16, 64), blk, 0, stream>>>(wl1, td_w2, wdec, BT, Cn, 64, t_dec);
    // 6. WKV recurrence
    rwkv_rec<<<dim3(Bn * Hn), blk, 0, stream>>>(rb, kb, vb, wdec, t_first, ybuf);
    // 7. GroupNorm + *g
    gn_mul<<<dim3(BT * Hn / 4), blk, 0, stream>>>(ybuf, gb, ln_w, ln_b, fin);
    // 8. output projection
    gemm_f32<0><<<dim3(16, 64), blk, 0, stream>>>(fin, Wo, out, BT, Cn, Cn, nullptr);
}

// Round 2
// 1316.826 us; speedup vs baseline: 1.5271x; 1.5271x over previous
//
#include <hip/hip_runtime.h>
#include <math.h>

// Problem constants
constexpr int Bn = 4, Tn = 1024, Cn = 1024, Hn = 16;
constexpr int BT = Bn * Tn;                 // 4096
constexpr long long BTC = (long long)BT * Cn;  // 4M elements
constexpr int CL = 64;                      // chunk length
constexpr int NC = Tn / CL;                 // 16 chunks

// ---------------------------------------------------------------------------
// Kernel 1: mix input for the token-mix LoRA: out = x + (x_prev - x)*x_maa[c]
// ---------------------------------------------------------------------------
__global__ __launch_bounds__(256) void prep_mixin(const float* __restrict__ x,
                                                  const float* __restrict__ x_maa,
                                                  float* __restrict__ out) {
    long long idx = (long long)blockIdx.x * 256 + threadIdx.x;
    if (idx >= BTC) return;
    int c  = (int)(idx & (Cn - 1));
    long long bt = idx >> 10;
    int t  = (int)(bt & (Tn - 1));
    float xv = x[idx];
    float xp = (t > 0) ? x[idx - Cn] : 0.f;
    out[idx] = xv + (xp - xv) * x_maa[c];
}

// ---------------------------------------------------------------------------
// Generic f32 tiled GEMM: C[M,N] = A[M,K] @ B[K,N], with epilogues.
// EPI: 0 none, 1 tanh, 2 silu, 3 logdecay (-exp(extra[col]+acc))
// ---------------------------------------------------------------------------
template <int EPI>
__global__ __launch_bounds__(256) void gemm_f32(const float* __restrict__ A,
                                                const float* __restrict__ Bm,
                                                float* __restrict__ C,
                                                int M, int N, int K,
                                                const float* __restrict__ extra) {
    __shared__ float As[16][64];
    __shared__ float Bs[16][64];
    int tid = threadIdx.x;
    int m0 = blockIdx.y * 64, n0 = blockIdx.x * 64;
    int tx = tid & 15, ty = tid >> 4;
    int ar = tid >> 2, ac = (tid & 3) * 4;   // A tile load coords
    int br = tid >> 4, bc = (tid & 15) * 4;  // B tile load coords
    float acc[4][4] = {};

    for (int k0 = 0; k0 < K; k0 += 16) {
        const float* ap = A + (size_t)(m0 + ar) * K + k0 + ac;
        float4 av = *reinterpret_cast<const float4*>(ap);
        As[ac + 0][ar] = av.x; As[ac + 1][ar] = av.y;
        As[ac + 2][ar] = av.z; As[ac + 3][ar] = av.w;
        float4 bv;
        if (n0 + bc + 3 < N) {
            bv = *reinterpret_cast<const float4*>(Bm + (size_t)(k0 + br) * N + n0 + bc);
        } else {
            float tmp[4];
            #pragma unroll
            for (int i = 0; i < 4; i++) {
                int col = n0 + bc + i;
                tmp[i] = (col < N) ? Bm[(size_t)(k0 + br) * N + col] : 0.f;
            }
            bv = make_float4(tmp[0], tmp[1], tmp[2], tmp[3]);
        }
        *reinterpret_cast<float4*>(&Bs[br][bc]) = bv;
        __syncthreads();
        #pragma unroll
        for (int kk = 0; kk < 16; kk++) {
            float4 a4 = *reinterpret_cast<const float4*>(&As[kk][ty * 4]);
            float4 b4 = *reinterpret_cast<const float4*>(&Bs[kk][tx * 4]);
            float aa[4] = {a4.x, a4.y, a4.z, a4.w};
            float bb[4] = {b4.x, b4.y, b4.z, b4.w};
            #pragma unroll
            for (int i = 0; i < 4; i++)
                #pragma unroll
                for (int j = 0; j < 4; j++)
                    acc[i][j] = fmaf(aa[i], bb[j], acc[i][j]);
        }
        __syncthreads();
    }

    #pragma unroll
    for (int i = 0; i < 4; i++) {
        int row = m0 + ty * 4 + i;
        #pragma unroll
        for (int j = 0; j < 4; j++) {
            int col = n0 + tx * 4 + j;
            if (col < N) {
                float v = acc[i][j];
                if (EPI == 1) v = tanhf(v);
                else if (EPI == 2) v = v / (1.f + expf(-v));        // silu
                else if (EPI == 3) v = -expf(extra[col] + v);       // log-decay
                C[(size_t)row * N + col] = v;
            }
        }
    }
}

// ---------------------------------------------------------------------------
// 5 mix deltas fused with wx/kx/vx/rx/gx build. One block per bt row.
// ---------------------------------------------------------------------------
__global__ __launch_bounds__(256) void deltas_mix(const float* __restrict__ x,
                                                  const float* __restrict__ mix160,
                                                  const float* __restrict__ w2,
                                                  const float* __restrict__ wmaa,
                                                  const float* __restrict__ kmaa,
                                                  const float* __restrict__ vmaa,
                                                  const float* __restrict__ rmaa,
                                                  const float* __restrict__ gmaa,
                                                  float* __restrict__ wx,
                                                  float* __restrict__ kx,
                                                  float* __restrict__ vx,
                                                  float* __restrict__ rx,
                                                  float* __restrict__ gx) {
    int bt = blockIdx.x;
    int t = bt & (Tn - 1);
    __shared__ float m[160];
    if (threadIdx.x < 160) m[threadIdx.x] = mix160[(size_t)bt * 160 + threadIdx.x];
    __syncthreads();
    for (int c = threadIdx.x; c < Cn; c += 256) {
        size_t idx = (size_t)bt * Cn + c;
        float xv = x[idx];
        float xp = (t > 0) ? x[idx - Cn] : 0.f;
        float sx = xp - xv;
        float d[5];
        #pragma unroll
        for (int f = 0; f < 5; f++) {
            float acc = 0.f;
            #pragma unroll
            for (int dd = 0; dd < 32; dd++)
                acc = fmaf(m[f * 32 + dd], w2[(size_t)(f * 32 + dd) * Cn + c], acc);
            d[f] = acc;
        }
        wx[idx] = xv + sx * (wmaa[c] + d[0]);
        kx[idx] = xv + sx * (kmaa[c] + d[1]);
        vx[idx] = xv + sx * (vmaa[c] + d[2]);
        rx[idx] = xv + sx * (rmaa[c] + d[3]);
        gx[idx] = xv + sx * (gmaa[c] + d[4]);
    }
}

// ---------------------------------------------------------------------------
// Chunked WKV scan, stage A: per (b,h,chunk) compute
//   Linc[t][ch] = inclusive prefix sum of lw over chunk
//   Wtot[ch]    = exp(Linc[63][ch])
//   Bc[k][v]    = sum_tau exp(Lend - Linc[tau]) * k_tau[k] * v_tau[v]
// Grid: B*H*NC = 1024 blocks.
// ---------------------------------------------------------------------------
__global__ __launch_bounds__(256) void chunk_summary(const float* __restrict__ kb,
                                                     const float* __restrict__ vb,
                                                     const float* __restrict__ lw,
                                                     float* __restrict__ LincG,
                                                     float* __restrict__ Bc,
                                                     float* __restrict__ Wtot) {
    int bid = blockIdx.x;
    int c = bid & 15, h = (bid >> 4) & 15, b = bid >> 8;
    size_t gbase = ((size_t)(b * Tn + c * CL) * Hn + h) * 64;
    int tid = threadIdx.x;
    __shared__ float linc[64][68];
    __shared__ float kd[64][68];
    __shared__ float vs[64][68];
    __shared__ float wtp[4][64];
    int wave = tid >> 6, lane = tid & 63;
    // blocked prefix sum over t, lane = channel
    {
        float acc = 0.f;
        #pragma unroll
        for (int i = 0; i < 16; i++) {
            int t = wave * 16 + i;
            acc += lw[gbase + (size_t)t * 1024 + lane];
            linc[t][lane] = acc;
        }
        wtp[wave][lane] = acc;
    }
    __syncthreads();
    {
        float off = 0.f;
        for (int g = 0; g < wave; g++) off += wtp[g][lane];
        #pragma unroll
        for (int i = 0; i < 16; i++) linc[wave * 16 + i][lane] += off;
    }
    __syncthreads();
    // write Linc to global; build kd (decayed-k) and vs tiles
    int t4 = tid >> 2, c0 = (tid & 3) * 16;
    #pragma unroll
    for (int i = 0; i < 4; i++) {
        int ch = c0 + i * 4;
        size_t ga = gbase + (size_t)t4 * 1024 + ch;
        float4 k4 = *reinterpret_cast<const float4*>(kb + ga);
        float4 v4 = *reinterpret_cast<const float4*>(vb + ga);
        float kk[4] = {k4.x, k4.y, k4.z, k4.w};
        float vv[4] = {v4.x, v4.y, v4.z, v4.w};
        float li[4], kdv[4];
        #pragma unroll
        for (int j = 0; j < 4; j++) {
            li[j] = linc[t4][ch + j];
            float lend = linc[63][ch + j];
            kdv[j] = kk[j] * expf(lend - li[j]);
            kd[t4][ch + j] = kdv[j];
            vs[t4][ch + j] = vv[j];
        }
        *reinterpret_cast<float4*>(LincG + (size_t)bid * 4096 + t4 * 64 + ch) =
            make_float4(li[0], li[1], li[2], li[3]);
    }
    if (tid < 64) Wtot[(size_t)bid * 64 + tid] = expf(linc[63][tid]);
    __syncthreads();
    // Bc[k][v] = sum_tau kd[tau][k] * vs[tau][v]
    int kk = tid >> 2, v0 = (tid & 3) * 16;
    float4 o[4] = {};
    for (int tau = 0; tau < 64; tau++) {
        float kdv = kd[tau][kk];
        #pragma unroll
        for (int j = 0; j < 4; j++) {
            float4 v4 = *reinterpret_cast<const float4*>(&vs[tau][v0 + 4 * j]);
            o[j].x = fmaf(kdv, v4.x, o[j].x);
            o[j].y = fmaf(kdv, v4.y, o[j].y);
            o[j].z = fmaf(kdv, v4.z, o[j].z);
            o[j].w = fmaf(kdv, v4.w, o[j].w);
        }
    }
    #pragma unroll
    for (int j = 0; j < 4; j++)
        *reinterpret_cast<float4*>(Bc + (size_t)bid * 4096 + kk * 64 + v0 + 4 * j) = o[j];
}

// ---------------------------------------------------------------------------
// Stage B: sequential scan over NC=16 chunk states.
// Sbuf[c] = state at chunk ENTRY. S <- Wtot*S + Bc.
// Grid: B*H*4 = 256 blocks; block handles [64 k][16 v].
// ---------------------------------------------------------------------------
__global__ __launch_bounds__(256) void chunk_scan(const float* __restrict__ Bc,
                                                  const float* __restrict__ Wtot,
                                                  float* __restrict__ Sbuf) {
    int bid = blockIdx.x;
    int bh = bid >> 2, vg = bid & 3;
    int kk = threadIdx.x >> 2;
    int v = vg * 16 + (threadIdx.x & 3) * 4;
    float4 S = make_float4(0.f, 0.f, 0.f, 0.f);
    for (int c = 0; c < NC; c++) {
        size_t cb = (size_t)(bh * NC + c) * 4096 + (size_t)kk * 64 + v;
        *reinterpret_cast<float4*>(Sbuf + cb) = S;
        float wt = Wtot[(size_t)(bh * NC + c) * 64 + kk];
        float4 b4 = *reinterpret_cast<const float4*>(Bc + cb);
        S.x = fmaf(wt, S.x, b4.x);
        S.y = fmaf(wt, S.y, b4.y);
        S.z = fmaf(wt, S.z, b4.z);
        S.w = fmaf(wt, S.w, b4.w);
    }
}

// ---------------------------------------------------------------------------
// Stage C: per (b,h,chunk) outputs:
//   Q'[t][k] = r*exp(Lexc),  K'[tau][k] = k*exp(-Linc)
//   A[t][tau] = Q'.K'  (tau<t);  A[t][t] = sum_k r*u*k;  A=0 above diag
//   Y = A @ V + Q' @ Sc
// ---------------------------------------------------------------------------
__global__ __launch_bounds__(256) void chunk_out(const float* __restrict__ rb,
                                                 const float* __restrict__ kb,
                                                 const float* __restrict__ vb,
                                                 const float* __restrict__ lw,
                                                 const float* __restrict__ LincG,
                                                 const float* __restrict__ Sbuf,
                                                 const float* __restrict__ tf,
                                                 float* __restrict__ y) {
    int bid = blockIdx.x;
    int c = bid & 15, h = (bid >> 4) & 15, b = bid >> 8;
    size_t gbase = ((size_t)(b * Tn + c * CL) * Hn + h) * 64;
    int tid = threadIdx.x;
    __shared__ float qs[64][68], ks[64][68], vs[64][68], as_[64][68], sc[64][68];
    __shared__ float diag[64];
    int t = tid >> 2, c0 = (tid & 3) * 16;
    float dpart = 0.f;
    #pragma unroll
    for (int i = 0; i < 4; i++) {
        int ch = c0 + i * 4;
        size_t ga = gbase + (size_t)t * 1024 + ch;
        float4 r4 = *reinterpret_cast<const float4*>(rb + ga);
        float4 k4 = *reinterpret_cast<const float4*>(kb + ga);
        float4 v4 = *reinterpret_cast<const float4*>(vb + ga);
        float4 l4 = *reinterpret_cast<const float4*>(lw + ga);
        float4 li4 = *reinterpret_cast<const float4*>(LincG + (size_t)bid * 4096 + t * 64 + ch);
        float4 u4 = *reinterpret_cast<const float4*>(tf + h * 64 + ch);
        float rr[4] = {r4.x, r4.y, r4.z, r4.w};
        float kkv[4] = {k4.x, k4.y, k4.z, k4.w};
        float vv[4] = {v4.x, v4.y, v4.z, v4.w};
        float lwv[4] = {l4.x, l4.y, l4.z, l4.w};
        float li[4] = {li4.x, li4.y, li4.z, li4.w};
        float uu[4] = {u4.x, u4.y, u4.z, u4.w};
        #pragma unroll
        for (int j = 0; j < 4; j++) {
            qs[t][ch + j] = rr[j] * expf(li[j] - lwv[j]);  // exp(Lexc)
            ks[t][ch + j] = kkv[j] * expf(-li[j]);
            vs[t][ch + j] = vv[j];
            dpart = fmaf(rr[j] * uu[j], kkv[j], dpart);
        }
        // load chunk-entry state (row index reused as k)
        float4 s4 = *reinterpret_cast<const float4*>(Sbuf + (size_t)bid * 4096 + t * 64 + ch);
        *reinterpret_cast<float4*>(&sc[t][ch]) = s4;
    }
    dpart += __shfl_xor(dpart, 1);
    dpart += __shfl_xor(dpart, 2);
    if ((tid & 3) == 0) diag[t] = dpart;
    __syncthreads();
    // scores: this thread computes tau = (tid&3) + 4*i, i=0..15
    {
        int tj = tid & 3;
        float acc[16];
        #pragma unroll
        for (int i = 0; i < 16; i++) acc[i] = 0.f;
        for (int ch = 0; ch < 64; ch += 4) {
            float4 q4 = *reinterpret_cast<const float4*>(&qs[t][ch]);
            #pragma unroll
            for (int i = 0; i < 16; i++) {
                int tau = tj + 4 * i;
                if (tau < t) {
                    float4 k4 = *reinterpret_cast<const float4*>(&ks[tau][ch]);
                    acc[i] += q4.x * k4.x + q4.y * k4.y + q4.z * k4.z + q4.w * k4.w;
                }
            }
        }
        #pragma unroll
        for (int i = 0; i < 16; i++) {
            int tau = tj + 4 * i;
            as_[t][tau] = (tau < t) ? acc[i] : (tau == t ? diag[t] : 0.f);
        }
    }
    __syncthreads();
    // output: Y[t][v] = sum_{tau<=t} A[t][tau]*V[tau][v] + sum_k Q'[t][k]*Sc[k][v]
    int v0 = (tid & 3) * 16;
    float4 o[4] = {};
    for (int tau = 0; tau <= t; tau++) {
        float av = as_[t][tau];
        #pragma unroll
        for (int j = 0; j < 4; j++) {
            float4 v4 = *reinterpret_cast<const float4*>(&vs[tau][v0 + 4 * j]);
            o[j].x = fmaf(av, v4.x, o[j].x);
            o[j].y = fmaf(av, v4.y, o[j].y);
            o[j].z = fmaf(av, v4.z, o[j].z);
            o[j].w = fmaf(av, v4.w, o[j].w);
        }
    }
    for (int k = 0; k < 64; k++) {
        float qv = qs[t][k];
        #pragma unroll
        for (int j = 0; j < 4; j++) {
            float4 s4 = *reinterpret_cast<const float4*>(&sc[k][v0 + 4 * j]);
            o[j].x = fmaf(qv, s4.x, o[j].x);
            o[j].y = fmaf(qv, s4.y, o[j].y);
            o[j].z = fmaf(qv, s4.z, o[j].z);
            o[j].w = fmaf(qv, s4.w, o[j].w);
        }
    }
    #pragma unroll
    for (int j = 0; j < 4; j++)
        *reinterpret_cast<float4*>(y + gbase + (size_t)t * 1024 + v0 + 4 * j) = o[j];
}

// ---------------------------------------------------------------------------
// GroupNorm per (bt,h) over 64 channels (after /8), *ln_w + ln_b, then *g.
// ---------------------------------------------------------------------------
__global__ __launch_bounds__(256) void gn_mul(const float* __restrict__ y,
                                              const float* __restrict__ g,
                                              const float* __restrict__ lnw,
                                              const float* __restrict__ lnb,
                                              float* __restrict__ fin) {
    int tid = threadIdx.x;
    int lane = tid & 63;
    int wv = tid >> 6;
    int grp = blockIdx.x * 4 + wv;    // bt*16 + h
    int h = grp & 15;
    size_t idx = (size_t)grp * 64 + lane;
    float val = y[idx] * 0.125f;
    float sum = val, sq = val * val;
    #pragma unroll
    for (int off = 32; off > 0; off >>= 1) {
        sum += __shfl_xor(sum, off, 64);
        sq  += __shfl_xor(sq,  off, 64);
    }
    float mu = sum * (1.f / 64.f);
    float var = sq * (1.f / 64.f) - mu * mu;
    float rs = rsqrtf(var + 1e-5f);
    float o = (val - mu) * rs * lnw[h * 64 + lane] + lnb[h * 64 + lane];
    fin[idx] = o * g[idx];
}

// ---------------------------------------------------------------------------
extern "C" void kernel_launch(void* const* d_in, const int* in_sizes, int n_in,
                              void* d_out, int out_size, void* d_ws, size_t ws_size,
                              hipStream_t stream) {
    (void)in_sizes; (void)n_in; (void)out_size; (void)ws_size;
    const float* x      = (const float*)d_in[0];
    const float* x_maa  = (const float*)d_in[1];
    const float* w_maa  = (const float*)d_in[2];
    const float* k_maa  = (const float*)d_in[3];
    const float* v_maa  = (const float*)d_in[4];
    const float* r_maa  = (const float*)d_in[5];
    const float* g_maa  = (const float*)d_in[6];
    const float* tm_w1  = (const float*)d_in[7];
    const float* tm_w2  = (const float*)d_in[8];
    const float* td_w1  = (const float*)d_in[9];
    const float* td_w2  = (const float*)d_in[10];
    const float* t_dec  = (const float*)d_in[11];
    const float* t_first= (const float*)d_in[12];
    const float* Wr     = (const float*)d_in[13];
    const float* Wk     = (const float*)d_in[14];
    const float* Wv     = (const float*)d_in[15];
    const float* Wg     = (const float*)d_in[16];
    const float* Wo     = (const float*)d_in[17];
    const float* ln_w   = (const float*)d_in[18];
    const float* ln_b   = (const float*)d_in[19];
    float* out = (float*)d_out;

    float* ws = (float*)d_ws;
    size_t off = 0;
    auto alloc = [&](size_t n) { float* p = ws + off; off += n; return p; };
    float* mixin  = alloc(BTC);
    float* mix160 = alloc((size_t)BT * 160);
    float* wx = alloc(BTC);
    float* kx = alloc(BTC);
    float* vx = alloc(BTC);
    float* rx = alloc(BTC);
    float* gx = alloc(BTC);
    float* kb = alloc(BTC);
    float* vb = alloc(BTC);
    float* gb = alloc(BTC);
    float* wl1 = alloc((size_t)BT * 64);
    // Reuse (stream-ordered; producer kernels complete before reuse):
    float* rb   = mixin;  // r projection (mixin dead after LoRA GEMM1)
    float* lwb  = vx;     // log-decay lw (vx dead after v projection)
    float* ybuf = wx;     // recurrence out (wx dead after decay-LoRA GEMM1)
    float* BcB  = rx;     // chunk contributions (rx dead after r projection)
    float* LiB  = gx;     // Linc prefix sums (gx dead after g projection)
    float* WtB  = wl1;    // chunk total decay (wl1 dead after decay GEMM2)
    float* SbB  = kx;     // chunk entry states (kx dead after k projection)
    float* fin  = kx;     // gn output (Sbuf dead after chunk_out)

    dim3 blk(256);
    prep_mixin<<<dim3((unsigned)((BTC + 255) / 256)), blk, 0, stream>>>(x, x_maa, mixin);
    gemm_f32<1><<<dim3(3, 64), blk, 0, stream>>>(mixin, tm_w1, mix160, BT, 160, Cn, nullptr);
    deltas_mix<<<dim3(BT), blk, 0, stream>>>(x, mix160, tm_w2,
                                             w_maa, k_maa, v_maa, r_maa, g_maa,
                                             wx, kx, vx, rx, gx);
    gemm_f32<0><<<dim3(16, 64), blk, 0, stream>>>(rx, Wr, rb, BT, Cn, Cn, nullptr);
    gemm_f32<0><<<dim3(16, 64), blk, 0, stream>>>(kx, Wk, kb, BT, Cn, Cn, nullptr);
    gemm_f32<0><<<dim3(16, 64), blk, 0, stream>>>(vx, Wv, vb, BT, Cn, Cn, nullptr);
    gemm_f32<2><<<dim3(16, 64), blk, 0, stream>>>(gx, Wg, gb, BT, Cn, Cn, nullptr);
    gemm_f32<1><<<dim3(1, 64), blk, 0, stream>>>(wx, td_w1, wl1, BT, 64, Cn, nullptr);
    gemm_f32<3><<<dim3(16, 64), blk, 0, stream>>>(wl1, td_w2, lwb, BT, Cn, 64, t_dec);
    // chunked scan
    chunk_summary<<<dim3(Bn * Hn * NC), blk, 0, stream>>>(kb, vb, lwb, LiB, BcB, WtB);
    chunk_scan<<<dim3(Bn * Hn * 4), blk, 0, stream>>>(BcB, WtB, SbB);
    chunk_out<<<dim3(Bn * Hn * NC), blk, 0, stream>>>(rb, kb, vb, lwb, LiB, SbB, t_first, ybuf);
    // epilogue
    gn_mul<<<dim3(BT * Hn / 4), blk, 0, stream>>>(ybuf, gb, ln_w, ln_b, fin);
    gemm_f32<0><<<dim3(16, 64), blk, 0, stream>>>(fin, Wo, out, BT, Cn, Cn, nullptr);
}